// Round 4
// 415.729 us; speedup vs baseline: 1.2258x; 1.2258x over previous
//
#include <hip/hip_runtime.h>

// TT-layer y = (c0 x c1 x c2 x c3) . x + bias, B=8192, all dims 8, ranks 16.
//
// Factorization: precompute (per launch, into d_ws, fp32->bf16):
//   CC [n1][q=(n2*16+r2)][p=(m1*8+m2)]   = sum_r1 c0[n1][m1][r1]*c1[r1][n2][m2][r2]   (8x128x64)
//   C23[row=(n3*8+n4)][s~(r2,m3,m4)]     = sum_r3 c2[r2][n3][m3][r3]*c3[r3][n4][m4]   (64x1024)
// Main kernel, 2 batch elems / block, per n1:
//   stage01: D1[q][(b',u)] = CC_n1 * xt      (M=128,N=128,K=64)  -> scatter to t2t
//   stage2 : y[row][(b',n2)] = C23 * t2t     (M=64, N=16, K=1024) -> +bias -> out
//
// Pipelined: double-buffered t2t (xt overlaid on buf1 -- dead after the
// one-time b01 load), ONE barrier per n1, a1 prefetch hidden under stage2,
// 4 MFMA accumulator chains in stage2.
// NOTE: packing uses pure-C++ f2bf (baseline-proven). A previous variant with
// inline-asm v_cvt_pk_bf16_f32 produced NaNs (suspected hipcc reordering
// around inline asm in unrolled MFMA code, cf. ISA-guide rule #18 family).

typedef __attribute__((ext_vector_type(8))) short bf16x8;
typedef __attribute__((ext_vector_type(4))) float f32x4;

__device__ __forceinline__ short f2bf(float f) {
    union { float f; unsigned u; } v; v.f = f;
    unsigned u = v.u;
    u += 0x7fffu + ((u >> 16) & 1u);   // round-to-nearest-even
    return (short)(u >> 16);
}

// ---------------- precompute kernel: build CC and C23 in d_ws ----------------
__global__ void tt_pre(const float* __restrict__ c0, const float* __restrict__ c1,
                       const float* __restrict__ c2, const float* __restrict__ c3,
                       short* __restrict__ ws) {
    int id = blockIdx.x * 256 + threadIdx.x;     // 0 .. 131071
    if (id < 65536) {
        // CC: id = n1*8192 + q*64 + p
        int p  = id & 63, q = (id >> 6) & 127, n1 = id >> 13;
        int m1 = p >> 3, m2 = p & 7, n2 = q >> 4, r2 = q & 15;
        float s = 0.f;
        #pragma unroll
        for (int r1 = 0; r1 < 16; ++r1)
            s += c0[(n1 * 8 + m1) * 16 + r1] * c1[((r1 * 8 + n2) * 8 + m2) * 16 + r2];
        ws[id] = f2bf(s);
    } else {
        // C23: id2 = row*1024 + s_, row=(n3*8+n4)
        int id2 = id - 65536;
        int s_  = id2 & 1023, row = id2 >> 10;
        int n3 = row >> 3, n4 = row & 7;
        int m3 = s_ >> 7, m4 = (s_ >> 4) & 7, r2s = s_ & 15;
        int r2 = (r2s - 4 * (m3 & 1)) & 15;      // inverse of scatter swizzle
        float s = 0.f;
        #pragma unroll
        for (int r3 = 0; r3 < 16; ++r3)
            s += c2[((r2 * 8 + n3) * 8 + m3) * 16 + r3] * c3[(r3 * 8 + n4) * 8 + m4];
        ws[65536 + id2] = f2bf(s);
    }
}

// ---------------- main kernel ----------------
#define XT_S 72      // xt row stride (shorts): 144B, 16B-aligned, +4 banks/row
#define T2_S 1032    // t2t row stride (shorts): 2064B, 16B-aligned, +4 banks/row
#define BUFSH (16 * T2_S)

__global__ __launch_bounds__(256, 2) void tt_main(
    const float* __restrict__ x, const short* __restrict__ ws,
    const float* __restrict__ bias, float* __restrict__ out)
{
    // t2t double buffer; xt (9216 shorts) overlays buf1 (dead after b01 load).
    __shared__ short lds2[2 * BUFSH];            // 66048 B

    const short* cc  = ws;               // [8][128][64]
    const short* c23 = ws + 65536;       // [64][1024]

    const int t = threadIdx.x, w = t >> 6, L = t & 63;
    const int quad = L >> 4, l16 = L & 15;
    const long long b0 = (long long)blockIdx.x * 2;
    const int mh = w >> 1, nh = w & 1;

    short* xt = lds2 + BUFSH;            // overlay: first buf1 scatter is n1=1,
                                         // which is two barriers after the b01 read.

    // ---- build xt (bf16, transposed): wave w -> b'=w>>1, p-range (w&1)*32..+31, u=L
    {
        const float* xb = x + (b0 + (w >> 1)) * 4096;
        const int pr = (w & 1) * 32;
        short* dst = &xt[(((w >> 1) * 64 + L) * XT_S) + pr];
        #pragma unroll
        for (int g = 0; g < 4; ++g) {
            bf16x8 v;
            #pragma unroll
            for (int j = 0; j < 8; ++j) v[j] = f2bf(xb[(pr + g * 8 + j) * 64 + L]);
            *(bf16x8*)(dst + g * 8) = v;
        }
    }

    // ---- persistent A2 frags (C23): wave w -> rows 16w..16w+15, full K=1024
    bf16x8 a2[32];
    {
        const short* base = c23 + (16 * w + l16) * 1024 + quad * 8;
        #pragma unroll
        for (int kt = 0; kt < 32; ++kt) a2[kt] = *(const bf16x8*)(base + kt * 32);
    }

    // ---- a1 prefetch (half of stage01 A): latency hides under barrier/stage2
    bf16x8 a1pf[4];
    auto pfload = [&](int n1) {
        const short* ab = cc + n1 * 8192 + (mh * 64 + l16) * 64 + quad * 8;
        a1pf[0] = *(const bf16x8*)(ab);              // kt=0, mt2=0
        a1pf[1] = *(const bf16x8*)(ab + 1024);       // kt=0, mt2=1
        a1pf[2] = *(const bf16x8*)(ab + 32);         // kt=1, mt2=0
        a1pf[3] = *(const bf16x8*)(ab + 1024 + 32);  // kt=1, mt2=1
    };
    pfload(0);

    __syncthreads();                     // B1: xt complete (all waves)

    // ---- persistent B01 frags (x): wave -> (mh, nh); nh picks b'
    bf16x8 b01[8];                       // [kt*4+nt]
    #pragma unroll
    for (int kt = 0; kt < 2; ++kt)
        #pragma unroll
        for (int nt = 0; nt < 4; ++nt)
            b01[kt * 4 + nt] =
                *(const bf16x8*)&xt[(nh * 64 + nt * 16 + l16) * XT_S + kt * 32 + quad * 8];

    __syncthreads();                     // B1b: all b01 reads done before any
                                         // future overwrite of the xt region.

    // ---- stage01 + scatter for one n1 (h=0 uses prefetched a1, h=1 loads fresh)
    // Split into two mt-halves to keep acc at 32 regs (VGPR budget).
    auto stage01 = [&](int n1, short* dst) {
        #pragma unroll
        for (int h = 0; h < 2; ++h) {
            bf16x8 a1[4];
            if (h == 0) {
                a1[0] = a1pf[0]; a1[1] = a1pf[1]; a1[2] = a1pf[2]; a1[3] = a1pf[3];
            } else {
                const short* ab = cc + n1 * 8192 + (mh * 64 + 32 + l16) * 64 + quad * 8;
                a1[0] = *(const bf16x8*)(ab);
                a1[1] = *(const bf16x8*)(ab + 1024);
                a1[2] = *(const bf16x8*)(ab + 32);
                a1[3] = *(const bf16x8*)(ab + 1024 + 32);
            }
            f32x4 acc[2][4] = {};
            #pragma unroll
            for (int mt2 = 0; mt2 < 2; ++mt2)
                #pragma unroll
                for (int nt = 0; nt < 4; ++nt) {
                    acc[mt2][nt] = __builtin_amdgcn_mfma_f32_16x16x32_bf16(
                        a1[mt2], b01[nt], acc[mt2][nt], 0, 0, 0);
                    acc[mt2][nt] = __builtin_amdgcn_mfma_f32_16x16x32_bf16(
                        a1[2 + mt2], b01[4 + nt], acc[mt2][nt], 0, 0, 0);
                }
            // scatter (b64 stores, swizzled s keeps i=0..3 contiguous)
            #pragma unroll
            for (int mt2 = 0; mt2 < 2; ++mt2) {
                const int n2 = mh * 4 + h * 2 + mt2;
                #pragma unroll
                for (int nt = 0; nt < 4; ++nt) {
                    const int u  = nt * 16 + l16;        // 0..63
                    const int m3 = u >> 3, m4 = u & 7;
                    const int rblk = (quad * 4 + 4 * (m3 & 1)) & 15;
                    int2 pk;
                    pk.x = (int)((unsigned short)f2bf(acc[mt2][nt][0]) |
                                 ((unsigned)(unsigned short)f2bf(acc[mt2][nt][1]) << 16));
                    pk.y = (int)((unsigned short)f2bf(acc[mt2][nt][2]) |
                                 ((unsigned)(unsigned short)f2bf(acc[mt2][nt][3]) << 16));
                    *(int2*)&dst[(nh * 8 + n2) * T2_S + (m3 * 8 + m4) * 16 + rblk] = pk;
                }
            }
        }
    };

    stage01(0, lds2);                    // fill buf0 with n1=0
    __syncthreads();                     // B2

    // ---- pipelined main loop: one barrier per n1
    #pragma unroll 1
    for (int k = 0; k < 8; ++k) {
        if (k < 7) pfload(k + 1);        // a1(k+1) L2 latency hides under stage2

        // ======== stage2(k): y = C23 * t2t[buf k&1], M=64 N=16 K=1024 ========
        f32x4 d0 = {}, d1 = {}, d2 = {}, d3 = {};
        {
            const short* tb = &lds2[(k & 1) * BUFSH + l16 * T2_S + quad * 8];
            __builtin_amdgcn_s_setprio(1);
            #pragma unroll
            for (int kt = 0; kt < 32; kt += 4) {
                bf16x8 f0 = *(const bf16x8*)(tb + kt * 32);
                bf16x8 f1 = *(const bf16x8*)(tb + kt * 32 + 32);
                bf16x8 f2 = *(const bf16x8*)(tb + kt * 32 + 64);
                bf16x8 f3 = *(const bf16x8*)(tb + kt * 32 + 96);
                d0 = __builtin_amdgcn_mfma_f32_16x16x32_bf16(a2[kt],     f0, d0, 0, 0, 0);
                d1 = __builtin_amdgcn_mfma_f32_16x16x32_bf16(a2[kt + 1], f1, d1, 0, 0, 0);
                d2 = __builtin_amdgcn_mfma_f32_16x16x32_bf16(a2[kt + 2], f2, d2, 0, 0, 0);
                d3 = __builtin_amdgcn_mfma_f32_16x16x32_bf16(a2[kt + 3], f3, d3, 0, 0, 0);
            }
            __builtin_amdgcn_s_setprio(0);
        }
        // ---- epilogue: rows 16w+quad*4+i, col l16=(b',n2); float4 out+bias
        {
            const int bp = l16 >> 3, n2 = l16 & 7;
            const int off = k * 512 + n2 * 64 + 16 * w + quad * 4;
            const float4 bv = *(const float4*)(bias + off);
            float4 ov;
            ov.x = d0[0] + d1[0] + d2[0] + d3[0] + bv.x;
            ov.y = d0[1] + d1[1] + d2[1] + d3[1] + bv.y;
            ov.z = d0[2] + d1[2] + d2[2] + d3[2] + bv.z;
            ov.w = d0[3] + d1[3] + d2[3] + d3[3] + bv.w;
            *(float4*)(out + (b0 + bp) * 4096 + off) = ov;
        }

        // ======== stage01(k+1) into the other buffer, then the ONE barrier ====
        if (k < 7) {
            stage01(k + 1, lds2 + ((k + 1) & 1) * BUFSH);
            __syncthreads();
        }
    }
}

extern "C" void kernel_launch(void* const* d_in, const int* in_sizes, int n_in,
                              void* d_out, int out_size, void* d_ws, size_t ws_size,
                              hipStream_t stream) {
    const float* x    = (const float*)d_in[0];
    const float* c0   = (const float*)d_in[1];
    const float* c1   = (const float*)d_in[2];
    const float* c2   = (const float*)d_in[3];
    const float* c3   = (const float*)d_in[4];
    const float* bias = (const float*)d_in[5];
    float* out = (float*)d_out;
    short* ws  = (short*)d_ws;           // 256 KB used: CC (128K) + C23 (128K)

    hipLaunchKernelGGL(tt_pre, dim3(512), dim3(256), 0, stream, c0, c1, c2, c3, ws);
    hipLaunchKernelGGL(tt_main, dim3(4096), dim3(256), 0, stream, x, ws, bias, out);
}